// Round 3
// baseline (6527.132 us; speedup 1.0000x reference)
//
#include <hip/hip_runtime.h>
#include <math.h>

#define B_ 256
#define T_ 256
#define RSS_ 12
#define L_ 256
#define FEAT_ 8
#define H_ 128
#define G4_ 512

// ---------------- workspace layout (float slots) ----------------
constexpr int OFF_W0T  = 0;                       // [108][512] Wih0^T
constexpr int OFF_U0T  = OFF_W0T + 108*512;       // [128][512] Whh0^T
constexpr int OFF_W1T  = OFF_U0T + 128*512;       // [128][512] Wih1^T
constexpr int OFF_U1T  = OFF_W1T + 128*512;       // [128][512] Whh1^T
constexpr int OFF_B0   = OFF_U1T + 128*512;       // [512] bih0+bhh0
constexpr int OFF_B1   = OFF_B0 + 512;            // [512] bih1+bhh1
constexpr int OFF_QW1T = OFF_B1 + 512;            // [4][64] q_W1^T
constexpr int OFF_FC1T = OFF_QW1T + 256;          // [128][64] fc_W1^T
constexpr int OFF_K2T  = OFF_FC1T + 8192;         // [64][256] folded keys (q_W2^T keys), transposed
constexpr int OFF_KB   = OFF_K2T + 64*256;        // [256] q_b2 . keys[l]
constexpr int OFF_LF   = OFF_KB + 256;            // [256][8] led_feat
constexpr int OFF_LPX  = OFF_LF + 2048;           // [256]
constexpr int OFF_LPY  = OFF_LPX + 256;           // [256]
constexpr int OFF_LPZ  = OFF_LPY + 256;           // [256]
constexpr int OFF_MEAN = OFF_LPZ + 256;           // [8] mean(led_feat) (cnt==0 fallback)
constexpr int OFF_PREV0= OFF_MEAN + 8;            // [4] initial prev_pos
constexpr int OFF_INT  = OFF_PREV0 + 4;           // int region: ledR[256], cnt[16], idx[12][256]

// ---------------- k_prep: transpose/pack weights ----------------
constexpr int S0=108*512, S1=128*512, S2=128*512, S3=128*512, S4=512, S5=512, S6=256, S7=128*64;
constexpr int TOT_T = S0+S1+S2+S3+S4+S5+S6+S7;

__global__ void k_prep(const float* __restrict__ Wih0, const float* __restrict__ Whh0,
                       const float* __restrict__ bih0, const float* __restrict__ bhh0,
                       const float* __restrict__ Wih1, const float* __restrict__ Whh1,
                       const float* __restrict__ bih1, const float* __restrict__ bhh1,
                       const float* __restrict__ qW1,  const float* __restrict__ fcW1,
                       float* __restrict__ ws) {
  for (int t = blockIdx.x*blockDim.x + threadIdx.x; t < TOT_T; t += gridDim.x*blockDim.x) {
    int u = t;
    if (u < S0) { int i=u>>9, j=u&511; ws[OFF_W0T+u] = Wih0[j*108+i]; continue; } u -= S0;
    if (u < S1) { int i=u>>9, j=u&511; ws[OFF_U0T+u] = Whh0[j*128+i]; continue; } u -= S1;
    if (u < S2) { int i=u>>9, j=u&511; ws[OFF_W1T+u] = Wih1[j*128+i]; continue; } u -= S2;
    if (u < S3) { int i=u>>9, j=u&511; ws[OFF_U1T+u] = Whh1[j*128+i]; continue; } u -= S3;
    if (u < S4) { ws[OFF_B0+u] = bih0[u]+bhh0[u]; continue; } u -= S4;
    if (u < S5) { ws[OFF_B1+u] = bih1[u]+bhh1[u]; continue; } u -= S5;
    if (u < S6) { int c=u>>6, j=u&63; ws[OFF_QW1T+u] = qW1[j*4+c]; continue; } u -= S6;
    { int i=u>>6, j=u&63; ws[OFF_FC1T+u] = fcW1[j*128+i]; }
  }
}

// ---------------- k_led: LED features / keys / freq lists ----------------
__global__ __launch_bounds__(256) void k_led(const float* __restrict__ gplf,
    const float* __restrict__ encW1, const float* __restrict__ encb1,
    const float* __restrict__ encW2, const float* __restrict__ encb2,
    const float* __restrict__ kW1, const float* __restrict__ kb1,
    const float* __restrict__ kW2, const float* __restrict__ kb2,
    const float* __restrict__ qW2, const float* __restrict__ qb2,
    float* __restrict__ ws) {
  __shared__ float sLF[L_][FEAT_];
  __shared__ float sP[L_][3];
  __shared__ int   sR[L_];
  const int l = threadIdx.x;
  const float p0=gplf[l*4+0], p1=gplf[l*4+1], p2=gplf[l*4+2], fr=gplf[l*4+3];

  float e1[32];
  for (int j=0;j<32;++j) {
    float v = encb1[j] + encW1[j*4+0]*p0 + encW1[j*4+1]*p1 + encW1[j*4+2]*p2 + encW1[j*4+3]*fr;
    e1[j] = fmaxf(v,0.f);
  }
  float lf[8];
  for (int f=0;f<8;++f) {
    float v = encb2[f];
    for (int j=0;j<32;++j) v += encW2[f*32+j]*e1[j];
    lf[f] = fmaxf(v,0.f);
  }
  float kin[11] = {lf[0],lf[1],lf[2],lf[3],lf[4],lf[5],lf[6],lf[7],p0,p1,p2};
  float hh[64];
  for (int j=0;j<64;++j) {
    float v = kb1[j];
    for (int c=0;c<11;++c) v += kW1[j*11+c]*kin[c];
    hh[j]=fmaxf(v,0.f);
  }
  float kk[64];
  for (int d=0;d<64;++d) {
    float v = kb2[d];
    for (int j=0;j<64;++j) v += kW2[d*64+j]*hh[j];
    kk[d]=v;
  }
  float kbv=0.f;
  for (int d=0;d<64;++d) kbv += qb2[d]*kk[d];
  ws[OFF_KB+l]=kbv;
  // folded key: k2[l][e] = sum_d qW2[d][e]*keys[l][d], stored transposed [e][l]
  for (int e=0;e<64;++e) {
    float acc=0.f;
    for (int d=0;d<64;++d) acc += qW2[d*64+e]*kk[d];
    ws[OFF_K2T+e*L_+l]=acc;
  }
  for (int f=0;f<8;++f){ ws[OFF_LF+l*8+f]=lf[f]; sLF[l][f]=lf[f]; }
  ws[OFF_LPX+l]=p0; ws[OFF_LPY+l]=p1; ws[OFF_LPZ+l]=p2;
  sP[l][0]=p0; sP[l][1]=p1; sP[l][2]=p2;
  const int r = (int)fr - 1;
  sR[l]=r;
  int* iws = (int*)(ws + OFF_INT);
  iws[l] = r;                               // ledR
  __syncthreads();
  if (l==0) {
    int* cntp = iws + 256;
    int* idxp = cntp + 16;
    int c[12]; for (int r2=0;r2<12;++r2) c[r2]=0;
    for (int i=0;i<L_;++i){ int r2=sR[i]; idxp[r2*256 + c[r2]] = i; c[r2]++; }
    for (int r2=0;r2<12;++r2) cntp[r2]=c[r2];
    float mx=0.f,my=0.f,mz=0.f;
    for (int i=0;i<L_;++i){mx+=sP[i][0];my+=sP[i][1];mz+=sP[i][2];}
    ws[OFF_PREV0+0]=mx/(float)L_; ws[OFF_PREV0+1]=my/(float)L_; ws[OFF_PREV0+2]=mz/(float)L_;
    for (int f=0;f<8;++f){ float s=0.f; for (int i=0;i<L_;++i) s+=sLF[i][f]; ws[OFF_MEAN+f]=s/(float)L_; }
  }
}

// ---------------- main recurrent kernel: 1 block per batch sample ----------------
__device__ __forceinline__ float sigf(float x){ return 1.f/(1.f+expf(-x)); }

__global__ __launch_bounds__(512) void k_main(const float* __restrict__ rss,
    const float* __restrict__ qb1, const float* __restrict__ lng, const float* __restrict__ lnb,
    const float* __restrict__ fcb1, const float* __restrict__ fcW2, const float* __restrict__ fcb2,
    const float* __restrict__ ws, float* __restrict__ out) {
  const int b = blockIdx.x, tid = threadIdx.x;
  const int lane = tid & 63, wave = tid >> 6;

  const float* W0T = ws+OFF_W0T;
  const float* U0T = ws+OFF_U0T;
  const float* W1T = ws+OFF_W1T;
  const float* U1T = ws+OFF_U1T;
  const float* B0  = ws+OFF_B0;
  const float* B1  = ws+OFF_B1;
  const float* QW1T= ws+OFF_QW1T;
  const float* FC1T= ws+OFF_FC1T;
  const float* K2T = ws+OFF_K2T;
  const float* KB  = ws+OFF_KB;
  const float* LF  = ws+OFF_LF;
  const float* LPX = ws+OFF_LPX;
  const float* LPY = ws+OFF_LPY;
  const float* LPZ = ws+OFF_LPZ;
  const float* MEANL = ws+OFF_MEAN;
  const int* ledR = (const int*)(ws+OFF_INT);
  const int* cntp = ledR+256;
  const int* idxp = cntp+16;

  __shared__ float sh0[H_], sc0v[H_], sh1[H_], sc1v[H_];
  __shared__ float sx[108];
  __shared__ float sa[12][65];      // +pad: stride 65 -> conflict-free cross-r reads
  __shared__ float ss[L_];
  __shared__ float sg[G4_];
  __shared__ float sy[H_];
  __shared__ float sf1[64];
  __shared__ float sprev[4];
  __shared__ float smv[2];

  if (tid < H_) { sh0[tid]=0.f; sc0v[tid]=0.f; sh1[tid]=0.f; sc1v[tid]=0.f; }
  if (tid < 3)  sprev[tid] = ws[OFF_PREV0+tid];
  __syncthreads();

  const float* rb = rss + (size_t)b*T_*RSS_;

  for (int t = 0; t < T_; ++t) {
    const float* rt = rb + t*RSS_;
    const float px = sprev[0], py = sprev[1], pz = sprev[2];

    // (a) relu(q_in @ q_W1^T + q_b1): 12x64 values
    for (int u = tid; u < 12*64; u += 512) {
      const int r = u >> 6, j = u & 63;
      float v = qb1[j] + rt[r]*QW1T[j] + px*QW1T[64+j] + py*QW1T[128+j] + pz*QW1T[192+j];
      sa[r][j] = fmaxf(v, 0.f);
    }
    __syncthreads();

    // (b) scores per LED (folded-key dot + distance-log term)
    if (tid < L_) {
      const int l = tid;
      const int r = ledR[l];
      float acc = KB[l];
      const float* ar = sa[r];
      #pragma unroll 16
      for (int e = 0; e < 64; ++e) acc = fmaf(ar[e], K2T[e*L_+l], acc);
      const float dx = px-LPX[l], dy = py-LPY[l], dz = pz-LPZ[l];
      acc -= 0.5f*logf(dx*dx+dy*dy+dz*dz + 1e-8f);
      ss[l] = acc;
    }
    __syncthreads();

    // (c) masked softmax + aggregation, one wave per frequency row
    for (int r = wave; r < 12; r += 8) {
      const int cnt = cntp[r];
      float vmax = -3.402823466e38f;
      for (int c = lane; c < cnt; c += 64) vmax = fmaxf(vmax, ss[idxp[r*256+c]]);
      #pragma unroll
      for (int o = 32; o > 0; o >>= 1) vmax = fmaxf(vmax, __shfl_xor(vmax, o));
      float psum=0.f, pf0=0.f,pf1=0.f,pf2=0.f,pf3=0.f,pf4=0.f,pf5=0.f,pf6=0.f,pf7=0.f;
      for (int c = lane; c < cnt; c += 64) {
        const int li = idxp[r*256+c];
        const float p = expf(ss[li]-vmax);
        psum += p;
        const float* lfp = LF + li*8;
        pf0 += p*lfp[0]; pf1 += p*lfp[1]; pf2 += p*lfp[2]; pf3 += p*lfp[3];
        pf4 += p*lfp[4]; pf5 += p*lfp[5]; pf6 += p*lfp[6]; pf7 += p*lfp[7];
      }
      #pragma unroll
      for (int o = 32; o > 0; o >>= 1) {
        psum += __shfl_xor(psum,o);
        pf0 += __shfl_xor(pf0,o); pf1 += __shfl_xor(pf1,o);
        pf2 += __shfl_xor(pf2,o); pf3 += __shfl_xor(pf3,o);
        pf4 += __shfl_xor(pf4,o); pf5 += __shfl_xor(pf5,o);
        pf6 += __shfl_xor(pf6,o); pf7 += __shfl_xor(pf7,o);
      }
      if (lane == 0) {
        sx[r*9+0] = rt[r];
        if (cnt > 0) {
          const float inv = 1.f/psum;
          sx[r*9+1] = pf0*inv; sx[r*9+2] = pf1*inv; sx[r*9+3] = pf2*inv; sx[r*9+4] = pf3*inv;
          sx[r*9+5] = pf4*inv; sx[r*9+6] = pf5*inv; sx[r*9+7] = pf6*inv; sx[r*9+8] = pf7*inv;
        } else {
          for (int f=0;f<8;++f) sx[r*9+1+f] = MEANL[f];
        }
      }
    }
    __syncthreads();

    // (d) LSTM0 gates: thread j owns gate j
    {
      float g = B0[tid];
      #pragma unroll 4
      for (int i = 0; i < 108; ++i) g = fmaf(sx[i], W0T[i*512+tid], g);
      #pragma unroll 4
      for (int i = 0; i < 128; ++i) g = fmaf(sh0[i], U0T[i*512+tid], g);
      sg[tid] = g;
    }
    __syncthreads();
    if (tid < H_) {
      const float ig = sigf(sg[tid]), fg = sigf(sg[H_+tid]);
      const float g2 = tanhf(sg[2*H_+tid]), og = sigf(sg[3*H_+tid]);
      const float c = fg*sc0v[tid] + ig*g2;
      sc0v[tid] = c;
      sh0[tid] = og*tanhf(c);
    }
    __syncthreads();

    // (e) LSTM1 gates
    {
      float g = B1[tid];
      #pragma unroll 4
      for (int i = 0; i < 128; ++i) g = fmaf(sh0[i], W1T[i*512+tid], fmaf(sh1[i], U1T[i*512+tid], g));
      sg[tid] = g;
    }
    __syncthreads();
    if (tid < H_) {
      const float ig = sigf(sg[tid]), fg = sigf(sg[H_+tid]);
      const float g2 = tanhf(sg[2*H_+tid]), og = sigf(sg[3*H_+tid]);
      const float c = fg*sc1v[tid] + ig*g2;
      sc1v[tid] = c;
      sh1[tid] = og*tanhf(c);
    }
    __syncthreads();

    // (f) LayerNorm stats (wave 0)
    if (tid < 64) {
      const float v0 = sh1[tid], v1 = sh1[tid+64];
      float s = v0+v1, q = v0*v0+v1*v1;
      #pragma unroll
      for (int o = 32; o > 0; o >>= 1) { s += __shfl_xor(s,o); q += __shfl_xor(q,o); }
      if (tid == 0) {
        const float mu = s*(1.f/128.f);
        const float var = q*(1.f/128.f) - mu*mu;
        smv[0] = mu;
        smv[1] = 1.f/sqrtf(var + 1e-5f);
      }
    }
    __syncthreads();
    if (tid < H_) sy[tid] = (sh1[tid]-smv[0])*smv[1]*lng[tid] + lnb[tid];
    __syncthreads();

    // (g) FC head
    if (tid < 64) {
      float acc = fcb1[tid];
      #pragma unroll 4
      for (int i = 0; i < 128; ++i) acc = fmaf(sy[i], FC1T[i*64+tid], acc);
      sf1[tid] = fmaxf(acc, 0.f);
    }
    __syncthreads();
    if (tid < 3) {
      float acc = fcb2[tid];
      const float* w = fcW2 + tid*64;
      #pragma unroll 8
      for (int j = 0; j < 64; ++j) acc = fmaf(sf1[j], w[j], acc);
      out[((size_t)b*T_+t)*3+tid] = acc;
      sprev[tid] = acc;
    }
    __syncthreads();
  }
}

extern "C" void kernel_launch(void* const* d_in, const int* in_sizes, int n_in,
                              void* d_out, int out_size, void* d_ws, size_t ws_size,
                              hipStream_t stream) {
  const float* rss   = (const float*)d_in[0];
  const float* gplf  = (const float*)d_in[1];
  const float* encW1 = (const float*)d_in[2];
  const float* encb1 = (const float*)d_in[3];
  const float* encW2 = (const float*)d_in[4];
  const float* encb2 = (const float*)d_in[5];
  const float* qW1   = (const float*)d_in[6];
  const float* qb1   = (const float*)d_in[7];
  const float* qW2   = (const float*)d_in[8];
  const float* qb2   = (const float*)d_in[9];
  const float* kW1   = (const float*)d_in[10];
  const float* kb1   = (const float*)d_in[11];
  const float* kW2   = (const float*)d_in[12];
  const float* kb2   = (const float*)d_in[13];
  const float* Wih0  = (const float*)d_in[14];
  const float* Whh0  = (const float*)d_in[15];
  const float* bih0  = (const float*)d_in[16];
  const float* bhh0  = (const float*)d_in[17];
  const float* Wih1  = (const float*)d_in[18];
  const float* Whh1  = (const float*)d_in[19];
  const float* bih1  = (const float*)d_in[20];
  const float* bhh1  = (const float*)d_in[21];
  const float* lng   = (const float*)d_in[22];
  const float* lnb   = (const float*)d_in[23];
  const float* fcW1  = (const float*)d_in[24];
  const float* fcb1  = (const float*)d_in[25];
  const float* fcW2  = (const float*)d_in[26];
  const float* fcb2  = (const float*)d_in[27];
  float* ws   = (float*)d_ws;
  float* outp = (float*)d_out;

  hipLaunchKernelGGL(k_prep, dim3(256), dim3(256), 0, stream,
                     Wih0,Whh0,bih0,bhh0,Wih1,Whh1,bih1,bhh1,qW1,fcW1,ws);
  hipLaunchKernelGGL(k_led, dim3(1), dim3(256), 0, stream,
                     gplf,encW1,encb1,encW2,encb2,kW1,kb1,kW2,kb2,qW2,qb2,ws);
  hipLaunchKernelGGL(k_main, dim3(B_), dim3(512), 0, stream,
                     rss,qb1,lng,lnb,fcb1,fcW2,fcb2,ws,outp);
}

// Round 4
// 4499.552 us; speedup vs baseline: 1.4506x; 1.4506x over previous
//
#include <hip/hip_runtime.h>
#include <math.h>

#define B_ 256
#define T_ 256
#define RSS_ 12
#define L_ 256
#define FEAT_ 8
#define H_ 128

// ---------------- workspace layout (float slots) ----------------
// WZ0: [60][512][4]  combined [x(108)|h0(128)] -> gate weights, chunk-major, padded to 240 inputs
// WZ1: [64][512][4]  combined [h0(128)|h1(128)] -> gate weights
constexpr int OFF_WZ0  = 0;                       // 60*512*4 = 122880
constexpr int OFF_WZ1  = OFF_WZ0 + 60*512*4;      // 64*512*4 = 131072
constexpr int OFF_B0   = OFF_WZ1 + 64*512*4;      // 512
constexpr int OFF_B1   = OFF_B0 + 512;            // 512
constexpr int OFF_QW1T = OFF_B1 + 512;            // [4][64]
constexpr int OFF_FC1T4= OFF_QW1T + 256;          // [32][64][4]
constexpr int OFF_K2T4 = OFF_FC1T4 + 32*64*4;     // [16][256][4]
constexpr int OFF_KB   = OFF_K2T4 + 16*256*4;     // [256]
constexpr int OFF_LF   = OFF_KB + 256;            // [256][8]
constexpr int OFF_LPX  = OFF_LF + 2048;           // [256]
constexpr int OFF_LPY  = OFF_LPX + 256;
constexpr int OFF_LPZ  = OFF_LPY + 256;
constexpr int OFF_MEAN = OFF_LPZ + 256;           // [8]
constexpr int OFF_PREV0= OFF_MEAN + 8;            // [4]
constexpr int OFF_INT  = OFF_PREV0 + 4;           // ints: ledR[256], cnt[16], idx[12][256]

// ---------------- k_prep ----------------
constexpr int SZ_WZ0=60*512*4, SZ_WZ1=64*512*4, SZ_B=512, SZ_Q=256, SZ_FC=32*64*4;
constexpr int TOT_T = SZ_WZ0+SZ_WZ1+SZ_B+SZ_B+SZ_Q+SZ_FC;

__global__ void k_prep(const float* __restrict__ Wih0, const float* __restrict__ Whh0,
                       const float* __restrict__ bih0, const float* __restrict__ bhh0,
                       const float* __restrict__ Wih1, const float* __restrict__ Whh1,
                       const float* __restrict__ bih1, const float* __restrict__ bhh1,
                       const float* __restrict__ qW1,  const float* __restrict__ fcW1,
                       float* __restrict__ ws) {
  for (int t = blockIdx.x*blockDim.x + threadIdx.x; t < TOT_T; t += gridDim.x*blockDim.x) {
    int u = t;
    if (u < SZ_WZ0) {
      const int c = u >> 11, rem = u & 2047, j = rem >> 2, k = rem & 3;
      const int i = (c<<2) + k;
      float v;
      if (i < 108) v = Wih0[j*108 + i];
      else if (i < 236) v = Whh0[j*128 + (i-108)];
      else v = 0.f;
      ws[OFF_WZ0 + u] = v; continue;
    } u -= SZ_WZ0;
    if (u < SZ_WZ1) {
      const int c = u >> 11, rem = u & 2047, j = rem >> 2, k = rem & 3;
      const int i = (c<<2) + k;
      ws[OFF_WZ1 + u] = (i < 128) ? Wih1[j*128 + i] : Whh1[j*128 + (i-128)];
      continue;
    } u -= SZ_WZ1;
    if (u < SZ_B) { ws[OFF_B0+u] = bih0[u]+bhh0[u]; continue; } u -= SZ_B;
    if (u < SZ_B) { ws[OFF_B1+u] = bih1[u]+bhh1[u]; continue; } u -= SZ_B;
    if (u < SZ_Q) { const int c=u>>6, j=u&63; ws[OFF_QW1T+u] = qW1[j*4+c]; continue; } u -= SZ_Q;
    { const int c = u >> 8, rem = u & 255, j = rem >> 2, k = rem & 3;
      ws[OFF_FC1T4 + u] = fcW1[j*128 + (c<<2) + k]; }
  }
}

// ---------------- k_led ----------------
__global__ __launch_bounds__(256) void k_led(const float* __restrict__ gplf,
    const float* __restrict__ encW1, const float* __restrict__ encb1,
    const float* __restrict__ encW2, const float* __restrict__ encb2,
    const float* __restrict__ kW1, const float* __restrict__ kb1,
    const float* __restrict__ kW2, const float* __restrict__ kb2,
    const float* __restrict__ qW2, const float* __restrict__ qb2,
    float* __restrict__ ws) {
  __shared__ float sLF[L_][FEAT_];
  __shared__ float sP[L_][3];
  __shared__ int   sR[L_];
  const int l = threadIdx.x;
  const float p0=gplf[l*4+0], p1=gplf[l*4+1], p2=gplf[l*4+2], fr=gplf[l*4+3];

  float e1[32];
  for (int j=0;j<32;++j) {
    float v = encb1[j] + encW1[j*4+0]*p0 + encW1[j*4+1]*p1 + encW1[j*4+2]*p2 + encW1[j*4+3]*fr;
    e1[j] = fmaxf(v,0.f);
  }
  float lf[8];
  for (int f=0;f<8;++f) {
    float v = encb2[f];
    for (int j=0;j<32;++j) v += encW2[f*32+j]*e1[j];
    lf[f] = fmaxf(v,0.f);
  }
  float kin[11] = {lf[0],lf[1],lf[2],lf[3],lf[4],lf[5],lf[6],lf[7],p0,p1,p2};
  float hh[64];
  for (int j=0;j<64;++j) {
    float v = kb1[j];
    for (int c=0;c<11;++c) v += kW1[j*11+c]*kin[c];
    hh[j]=fmaxf(v,0.f);
  }
  float kk[64];
  for (int d=0;d<64;++d) {
    float v = kb2[d];
    for (int j=0;j<64;++j) v += kW2[d*64+j]*hh[j];
    kk[d]=v;
  }
  float kbv=0.f;
  for (int d=0;d<64;++d) kbv += qb2[d]*kk[d];
  ws[OFF_KB+l]=kbv;
  // folded key k2[l][e] = sum_d qW2[d][e]*kk[d]; store as [e/4][l][e%4] for float4 loads
  for (int e=0;e<64;++e) {
    float acc=0.f;
    for (int d=0;d<64;++d) acc += qW2[d*64+e]*kk[d];
    ws[OFF_K2T4 + (e>>2)*1024 + l*4 + (e&3)] = acc;
  }
  for (int f=0;f<8;++f){ ws[OFF_LF+l*8+f]=lf[f]; sLF[l][f]=lf[f]; }
  ws[OFF_LPX+l]=p0; ws[OFF_LPY+l]=p1; ws[OFF_LPZ+l]=p2;
  sP[l][0]=p0; sP[l][1]=p1; sP[l][2]=p2;
  const int r = (int)fr - 1;
  sR[l]=r;
  int* iws = (int*)(ws + OFF_INT);
  iws[l] = r;
  __syncthreads();
  if (l==0) {
    int* cntp = iws + 256;
    int* idxp = cntp + 16;
    int c[12]; for (int r2=0;r2<12;++r2) c[r2]=0;
    for (int i=0;i<L_;++i){ int r2=sR[i]; idxp[r2*256 + c[r2]] = i; c[r2]++; }
    for (int r2=0;r2<12;++r2) cntp[r2]=c[r2];
    float mx=0.f,my=0.f,mz=0.f;
    for (int i=0;i<L_;++i){mx+=sP[i][0];my+=sP[i][1];mz+=sP[i][2];}
    ws[OFF_PREV0+0]=mx/(float)L_; ws[OFF_PREV0+1]=my/(float)L_; ws[OFF_PREV0+2]=mz/(float)L_;
    for (int f=0;f<8;++f){ float s=0.f; for (int i=0;i<L_;++i) s+=sLF[i][f]; ws[OFF_MEAN+f]=s/(float)L_; }
  }
}

// ---------------- main recurrent kernel: 1 block (1024 thr) per batch sample ----------------
__device__ __forceinline__ float sigf(float x){ return 1.f/(1.f+expf(-x)); }

__global__ __launch_bounds__(1024,4) void k_main(const float* __restrict__ rss,
    const float* __restrict__ qb1, const float* __restrict__ lng, const float* __restrict__ lnb,
    const float* __restrict__ fcb1, const float* __restrict__ fcW2, const float* __restrict__ fcb2,
    const float* __restrict__ ws, float* __restrict__ out) {
  const int b = blockIdx.x, tid = threadIdx.x;
  const int lane = tid & 63, wave = tid >> 6;

  __shared__ float srss[T_*12];
  __shared__ float sLF[2048];
  __shared__ float sLPx[256], sLPy[256], sLPz[256];
  __shared__ float sKB[256];
  __shared__ float sB0[512], sB1[512];
  __shared__ float sQ[256], sqb1v[64];
  __shared__ float sLNG[128], sLNB[128];
  __shared__ float sfcb1[64], sfcW2v[192], sfcb2v[3];
  __shared__ float sMEANv[8];
  __shared__ float sz0[240];       // [0..107]=x (r*9 blocks), [108..235]=h0, [236..239]=pad 0
  __shared__ float sz1[256];       // [0..127]=h0, [128..255]=h1
  __shared__ float sc0[128], sc1[128];
  __shared__ float sa[12][68];     // row stride 68 floats (16B aligned) for float4 reads
  __shared__ float ssv[256];
  __shared__ float sgp[2][512];
  __shared__ float syv[128];
  __shared__ float sprev[3];
  __shared__ int   sledR[256], scnt[12], sidx[12*256];

  // -------- one-time staging --------
  const float* rb = rss + (size_t)b*T_*12;
  for (int u=tid; u<T_*12; u+=1024) srss[u]=rb[u];
  for (int u=tid; u<2048; u+=1024) sLF[u]=ws[OFF_LF+u];
  if (tid<256){ sLPx[tid]=ws[OFF_LPX+tid]; sLPy[tid]=ws[OFF_LPY+tid]; sLPz[tid]=ws[OFF_LPZ+tid];
                sKB[tid]=ws[OFF_KB+tid]; sQ[tid]=ws[OFF_QW1T+tid]; }
  if (tid<512){ sB0[tid]=ws[OFF_B0+tid]; sB1[tid]=ws[OFF_B1+tid]; }
  if (tid<64){ sqb1v[tid]=qb1[tid]; sfcb1[tid]=fcb1[tid]; }
  if (tid<128){ sLNG[tid]=lng[tid]; sLNB[tid]=lnb[tid]; }
  if (tid<192) sfcW2v[tid]=fcW2[tid];
  if (tid<3){ sfcb2v[tid]=fcb2[tid]; sprev[tid]=ws[OFF_PREV0+tid]; }
  if (tid<8) sMEANv[tid]=ws[OFF_MEAN+tid];
  {
    const int* iws=(const int*)(ws+OFF_INT);
    if (tid<256) sledR[tid]=iws[tid];
    if (tid<12) scnt[tid]=iws[256+tid];
    for (int u=tid; u<12*256; u+=1024) sidx[u]=iws[272+u];
  }
  if (tid<128){ sc0[tid]=0.f; sc1[tid]=0.f; sz1[tid]=0.f; sz1[128+tid]=0.f; }
  if (tid<132) sz0[108+tid]=0.f;
  __syncthreads();

  const float4* WZ0 = (const float4*)(ws+OFF_WZ0);
  const float4* WZ1 = (const float4*)(ws+OFF_WZ1);
  const float4* FC4 = (const float4*)(ws+OFF_FC1T4);
  const float4* K4  = (const float4*)(ws+OFF_K2T4);

  for (int t = 0; t < T_; ++t) {
    const float px = sprev[0], py = sprev[1], pz = sprev[2];

    // (a) relu(q_in @ q_W1^T + q_b1): 12x64, one thread each
    if (tid < 768) {
      const int r = tid >> 6, j = tid & 63;
      const float x = srss[t*12+r];
      float v = sqb1v[j] + x*sQ[j] + px*sQ[64+j] + py*sQ[128+j] + pz*sQ[192+j];
      sa[r][j] = fmaxf(v, 0.f);
    }
    __syncthreads();

    // (b) scores per LED: folded-key dot (float4) + distance-log
    if (tid < 256) {
      const int l = tid, r = sledR[l];
      float acc = sKB[l];
      const float4* ar4 = (const float4*)&sa[r][0];
      #pragma unroll
      for (int c = 0; c < 16; ++c) {
        const float4 w = K4[c*256 + l];
        const float4 a = ar4[c];
        acc = fmaf(a.x, w.x, acc); acc = fmaf(a.y, w.y, acc);
        acc = fmaf(a.z, w.z, acc); acc = fmaf(a.w, w.w, acc);
      }
      const float dx = px-sLPx[l], dy = py-sLPy[l], dz = pz-sLPz[l];
      acc -= 0.5f*logf(dx*dx+dy*dy+dz*dz + 1e-8f);
      ssv[l] = acc;
    }
    __syncthreads();

    // (c) masked softmax + aggregation: wave r handles frequency row r
    if (wave < 12) {
      const int r = wave, cnt = scnt[r];
      float vmax = -3.402823466e38f;
      for (int c = lane; c < cnt; c += 64) vmax = fmaxf(vmax, ssv[sidx[r*256+c]]);
      #pragma unroll
      for (int o = 32; o > 0; o >>= 1) vmax = fmaxf(vmax, __shfl_xor(vmax, o));
      float ps=0.f, p0=0.f,p1=0.f,p2=0.f,p3=0.f,p4=0.f,p5=0.f,p6=0.f,p7=0.f;
      for (int c = lane; c < cnt; c += 64) {
        const int li = sidx[r*256+c];
        const float p = expf(ssv[li]-vmax);
        ps += p;
        const float* lf = sLF + li*8;
        p0 += p*lf[0]; p1 += p*lf[1]; p2 += p*lf[2]; p3 += p*lf[3];
        p4 += p*lf[4]; p5 += p*lf[5]; p6 += p*lf[6]; p7 += p*lf[7];
      }
      #pragma unroll
      for (int o = 32; o > 0; o >>= 1) {
        ps += __shfl_xor(ps,o);
        p0 += __shfl_xor(p0,o); p1 += __shfl_xor(p1,o);
        p2 += __shfl_xor(p2,o); p3 += __shfl_xor(p3,o);
        p4 += __shfl_xor(p4,o); p5 += __shfl_xor(p5,o);
        p6 += __shfl_xor(p6,o); p7 += __shfl_xor(p7,o);
      }
      if (lane == 0) {
        sz0[r*9+0] = srss[t*12+r];
        if (cnt > 0) {
          const float inv = 1.f/ps;
          sz0[r*9+1]=p0*inv; sz0[r*9+2]=p1*inv; sz0[r*9+3]=p2*inv; sz0[r*9+4]=p3*inv;
          sz0[r*9+5]=p4*inv; sz0[r*9+6]=p5*inv; sz0[r*9+7]=p6*inv; sz0[r*9+8]=p7*inv;
        } else {
          for (int f=0;f<8;++f) sz0[r*9+1+f] = sMEANv[f];
        }
      }
    }
    __syncthreads();

    // (d1) LSTM0 gate partials: 2 half-threads per gate, float4 weight stream
    {
      const int j = tid & 511, h = tid >> 9;
      float g = h ? 0.f : sB0[j];
      const int cb = h ? 30 : 0, ce = h ? 60 : 30;
      #pragma unroll 6
      for (int c = cb; c < ce; ++c) {
        const float4 w = WZ0[c*512 + j];
        const float* z = sz0 + (c<<2);
        g = fmaf(w.x, z[0], g); g = fmaf(w.y, z[1], g);
        g = fmaf(w.z, z[2], g); g = fmaf(w.w, z[3], g);
      }
      sgp[h][j] = g;
    }
    __syncthreads();

    // (d2) LSTM0 nonlinearity
    if (tid < 128) {
      const int u = tid;
      const float gi = sgp[0][u]     + sgp[1][u];
      const float gf = sgp[0][128+u] + sgp[1][128+u];
      const float gg = sgp[0][256+u] + sgp[1][256+u];
      const float go = sgp[0][384+u] + sgp[1][384+u];
      const float c = sigf(gf)*sc0[u] + sigf(gi)*tanhf(gg);
      sc0[u] = c;
      const float hn = sigf(go)*tanhf(c);
      sz0[108+u] = hn; sz1[u] = hn;
    }
    __syncthreads();

    // (e1) LSTM1 gate partials
    {
      const int j = tid & 511, h = tid >> 9;
      float g = h ? 0.f : sB1[j];
      const int cb = h ? 32 : 0, ce = h ? 64 : 32;
      #pragma unroll 8
      for (int c = cb; c < ce; ++c) {
        const float4 w = WZ1[c*512 + j];
        const float* z = sz1 + (c<<2);
        g = fmaf(w.x, z[0], g); g = fmaf(w.y, z[1], g);
        g = fmaf(w.z, z[2], g); g = fmaf(w.w, z[3], g);
      }
      sgp[h][j] = g;
    }
    __syncthreads();

    // (e2) LSTM1 nonlinearity
    if (tid < 128) {
      const int u = tid;
      const float gi = sgp[0][u]     + sgp[1][u];
      const float gf = sgp[0][128+u] + sgp[1][128+u];
      const float gg = sgp[0][256+u] + sgp[1][256+u];
      const float go = sgp[0][384+u] + sgp[1][384+u];
      const float c = sigf(gf)*sc1[u] + sigf(gi)*tanhf(gg);
      sc1[u] = c;
      sz1[128+u] = sigf(go)*tanhf(c);
    }
    __syncthreads();

    // (f) LayerNorm: stats + normalize in one wave
    if (tid < 64) {
      const float v0 = sz1[128+tid], v1 = sz1[192+tid];
      float s = v0+v1, q = v0*v0+v1*v1;
      #pragma unroll
      for (int o = 32; o > 0; o >>= 1) { s += __shfl_xor(s,o); q += __shfl_xor(q,o); }
      const float mu = s*(1.f/128.f);
      const float rs = 1.f/sqrtf(q*(1.f/128.f) - mu*mu + 1e-5f);
      syv[tid]    = (v0-mu)*rs*sLNG[tid]    + sLNB[tid];
      syv[tid+64] = (v1-mu)*rs*sLNG[tid+64] + sLNB[tid+64];
    }
    __syncthreads();

    // (g) FC head: FC1 per-thread + FC2 via butterfly reduce
    if (tid < 64) {
      float acc = sfcb1[tid];
      #pragma unroll 8
      for (int c = 0; c < 32; ++c) {
        const float4 w = FC4[c*64 + tid];
        const float* z = syv + (c<<2);
        acc = fmaf(w.x, z[0], acc); acc = fmaf(w.y, z[1], acc);
        acc = fmaf(w.z, z[2], acc); acc = fmaf(w.w, z[3], acc);
      }
      const float f1 = fmaxf(acc, 0.f);
      float a0 = sfcW2v[tid]*f1, a1 = sfcW2v[64+tid]*f1, a2 = sfcW2v[128+tid]*f1;
      #pragma unroll
      for (int o = 32; o > 0; o >>= 1) {
        a0 += __shfl_xor(a0,o); a1 += __shfl_xor(a1,o); a2 += __shfl_xor(a2,o);
      }
      if (tid < 3) {
        const float r = (tid==0 ? a0 : (tid==1 ? a1 : a2)) + sfcb2v[tid];
        out[((size_t)b*T_+t)*3+tid] = r;
        sprev[tid] = r;
      }
    }
    __syncthreads();
  }
}

extern "C" void kernel_launch(void* const* d_in, const int* in_sizes, int n_in,
                              void* d_out, int out_size, void* d_ws, size_t ws_size,
                              hipStream_t stream) {
  const float* rss   = (const float*)d_in[0];
  const float* gplf  = (const float*)d_in[1];
  const float* encW1 = (const float*)d_in[2];
  const float* encb1 = (const float*)d_in[3];
  const float* encW2 = (const float*)d_in[4];
  const float* encb2 = (const float*)d_in[5];
  const float* qW1   = (const float*)d_in[6];
  const float* qb1   = (const float*)d_in[7];
  const float* qW2   = (const float*)d_in[8];
  const float* qb2   = (const float*)d_in[9];
  const float* kW1   = (const float*)d_in[10];
  const float* kb1   = (const float*)d_in[11];
  const float* kW2   = (const float*)d_in[12];
  const float* kb2   = (const float*)d_in[13];
  const float* Wih0  = (const float*)d_in[14];
  const float* Whh0  = (const float*)d_in[15];
  const float* bih0  = (const float*)d_in[16];
  const float* bhh0  = (const float*)d_in[17];
  const float* Wih1  = (const float*)d_in[18];
  const float* Whh1  = (const float*)d_in[19];
  const float* bih1  = (const float*)d_in[20];
  const float* bhh1  = (const float*)d_in[21];
  const float* lng   = (const float*)d_in[22];
  const float* lnb   = (const float*)d_in[23];
  const float* fcW1  = (const float*)d_in[24];
  const float* fcb1  = (const float*)d_in[25];
  const float* fcW2  = (const float*)d_in[26];
  const float* fcb2  = (const float*)d_in[27];
  float* ws   = (float*)d_ws;
  float* outp = (float*)d_out;

  hipLaunchKernelGGL(k_prep, dim3(256), dim3(256), 0, stream,
                     Wih0,Whh0,bih0,bhh0,Wih1,Whh1,bih1,bhh1,qW1,fcW1,ws);
  hipLaunchKernelGGL(k_led, dim3(1), dim3(256), 0, stream,
                     gplf,encW1,encb1,encW2,encb2,kW1,kb1,kW2,kb2,qW2,qb2,ws);
  hipLaunchKernelGGL(k_main, dim3(B_), dim3(1024), 0, stream,
                     rss,qb1,lng,lnb,fcb1,fcW2,fcb2,ws,outp);
}